// Round 2
// baseline (12.080 us; speedup 1.0000x reference)
//
#include <hip/hip_runtime.h>

// Ball query: for each query q in pc1 (8192 x 3), find the FIRST K=10 points of
// pc2 (32768 x 3) within radius 0.25, in ascending index order.
// Output (float* buffer, tuple concatenated flat):
//   [0 .. 81920)            mapping as float  (index or -1.0f), shape (8192,10)
//   [81920 .. 327680)       gathered points,  shape (8192,10,3) (0 for invalid)
//
// One 64-lane wave per query; 128 points per iteration (2 per lane) with a
// 1-deep manual prefetch so the next chunk's loads are in flight before the
// data-dependent early-exit check. Ballot + prefix-popcount assigns in-order
// output slots. Worst case (corner query, ~0.8% hit rate): ~10 iterations.

#define N1 8192
#define N2 32768
#define KNN 10
#define R2 0.0625f
#define CH 128   // points per iteration (2 per lane)

__global__ __launch_bounds__(256) void ball_query_kernel(
    const float* __restrict__ qp,   // [N1*3]
    const float* __restrict__ pp,   // [N2*3]
    float* __restrict__ out)
{
    const int lane = threadIdx.x & 63;
    const int qid  = blockIdx.x * 4 + (threadIdx.x >> 6);

    const float qx = qp[qid * 3 + 0];
    const float qy = qp[qid * 3 + 1];
    const float qz = qp[qid * 3 + 2];

    float* __restrict__ map_out = out + (size_t)qid * KNN;
    float* __restrict__ pts_out = out + (size_t)N1 * KNN + (size_t)qid * KNN * 3;

    int count = 0;
    int base  = 0;

    // current-chunk registers: point a = base+lane, point b = base+64+lane
    float ax, ay, az, bx, by, bz;
    {
        const float* pa = pp + (size_t)(base + lane) * 3;
        ax = pa[0]; ay = pa[1]; az = pa[2];
        const float* pb = pp + (size_t)(base + 64 + lane) * 3;
        bx = pb[0]; by = pb[1]; bz = pb[2];
    }

    for (;;) {
        // ---- prefetch next chunk (wave-uniform branch) ----
        const int nb = base + CH;
        const bool have_next = (nb < N2);
        float cx = 0.f, cy = 0.f, cz = 0.f, ex = 0.f, ey = 0.f, ez = 0.f;
        if (have_next) {
            const float* pc = pp + (size_t)(nb + lane) * 3;
            cx = pc[0]; cy = pc[1]; cz = pc[2];
            const float* pe = pp + (size_t)(nb + 64 + lane) * 3;
            ex = pe[0]; ey = pe[1]; ez = pe[2];
        }

        // ---- process current chunk ----
        const float dax = ax - qx, day = ay - qy, daz = az - qz;
        const float d2a = dax * dax + day * day + daz * daz;
        const bool wa = d2a < R2;
        const unsigned long long m0 = __ballot(wa);
        if (wa) {
            const int slot = count + __popcll(m0 & ((1ull << lane) - 1ull));
            if (slot < KNN) {
                map_out[slot]         = (float)(base + lane);
                pts_out[slot * 3 + 0] = ax;
                pts_out[slot * 3 + 1] = ay;
                pts_out[slot * 3 + 2] = az;
            }
        }
        const int c0 = __popcll(m0);

        const float dbx = bx - qx, dby = by - qy, dbz = bz - qz;
        const float d2b = dbx * dbx + dby * dby + dbz * dbz;
        const bool wb = d2b < R2;
        const unsigned long long m1 = __ballot(wb);
        if (wb) {
            const int slot = count + c0 + __popcll(m1 & ((1ull << lane) - 1ull));
            if (slot < KNN) {
                map_out[slot]         = (float)(base + 64 + lane);
                pts_out[slot * 3 + 0] = bx;
                pts_out[slot * 3 + 1] = by;
                pts_out[slot * 3 + 2] = bz;
            }
        }
        count += c0 + __popcll(m1);

        if (count >= KNN || !have_next) break;   // uniform across the wave

        ax = cx; ay = cy; az = cz;
        bx = ex; by = ey; bz = ez;
        base = nb;
    }

    // Fill unfilled tail slots: mapping = -1, pts = 0. Must write every call
    // (harness poisons d_out once and never re-poisons between replays).
    if (count < KNN && lane >= count && lane < KNN) {
        map_out[lane]         = -1.0f;
        pts_out[lane * 3 + 0] = 0.0f;
        pts_out[lane * 3 + 1] = 0.0f;
        pts_out[lane * 3 + 2] = 0.0f;
    }
}

extern "C" void kernel_launch(void* const* d_in, const int* in_sizes, int n_in,
                              void* d_out, int out_size, void* d_ws, size_t ws_size,
                              hipStream_t stream) {
    const float* pc1 = (const float*)d_in[0];   // (1, 8192, 3)  queries
    const float* pc2 = (const float*)d_in[1];   // (1, 32768, 3) points
    float* out = (float*)d_out;

    dim3 grid(N1 / 4);    // 4 waves per 256-thread block, one wave per query
    dim3 block(256);
    ball_query_kernel<<<grid, block, 0, stream>>>(pc1, pc2, out);
}

// Round 3
// 11.288 us; speedup vs baseline: 1.0702x; 1.0702x over previous
//
#include <hip/hip_runtime.h>

// Ball query: for each query q in pc1 (8192 x 3), find the FIRST K=10 points of
// pc2 (32768 x 3) within radius 0.25, in ascending index order.
// Output (float* buffer, tuple concatenated flat):
//   [0 .. 81920)            mapping as float  (index or -1.0f), shape (8192,10)
//   [81920 .. 327680)       gathered points,  shape (8192,10,3) (0 for invalid)
//
// One 64-lane wave per query; 256 points per iteration (4 per lane).
// Ballot + prefix-popcount assigns in-order output slots; wave-uniform early
// exit once 10 hits are found. Typical interior query (hit rate ~6.5%) exits
// after ONE iteration; worst corner query after ~6.
//
// R1/R2 established: 64-pt chunks = 11.5 us, 128-pt + prefetch = 12.1 us ->
// execution is a small fraction; this round probes whether iteration count
// matters at all before declaring the launch-overhead floor.

#define N1 8192
#define N2 32768
#define KNN 10
#define R2 0.0625f

__global__ __launch_bounds__(256) void ball_query_kernel(
    const float* __restrict__ qp,   // [N1*3]
    const float* __restrict__ pp,   // [N2*3]
    float* __restrict__ out)
{
    const int lane = threadIdx.x & 63;
    const int qid  = blockIdx.x * 4 + (threadIdx.x >> 6);

    const float qx = qp[qid * 3 + 0];
    const float qy = qp[qid * 3 + 1];
    const float qz = qp[qid * 3 + 2];

    float* __restrict__ map_out = out + (size_t)qid * KNN;
    float* __restrict__ pts_out = out + (size_t)N1 * KNN + (size_t)qid * KNN * 3;

    int count = 0;
    for (int base = 0; base < N2 && count < KNN; base += 256) {
        #pragma unroll
        for (int s = 0; s < 4; ++s) {
            const int i = base + s * 64 + lane;     // N2 % 256 == 0: in bounds
            const float* p = pp + (size_t)i * 3;
            const float px = p[0], py = p[1], pz = p[2];
            const float dx = px - qx, dy = py - qy, dz = pz - qz;
            const float d2 = dx * dx + dy * dy + dz * dz;
            const bool within = d2 < R2;
            const unsigned long long m = __ballot(within);
            if (within) {
                const int slot = count + __popcll(m & ((1ull << lane) - 1ull));
                if (slot < KNN) {
                    map_out[slot]         = (float)i;
                    pts_out[slot * 3 + 0] = px;
                    pts_out[slot * 3 + 1] = py;
                    pts_out[slot * 3 + 2] = pz;
                }
            }
            count += __popcll(m);
        }
    }

    // Fill unfilled tail slots: mapping = -1, pts = 0. Must write every call
    // (harness poisons d_out once and never re-poisons between replays).
    // (With this data every query has >=10 in-radius points, but keep it for
    // correctness under any input.)
    if (count < KNN && lane >= count && lane < KNN) {
        map_out[lane]         = -1.0f;
        pts_out[lane * 3 + 0] = 0.0f;
        pts_out[lane * 3 + 1] = 0.0f;
        pts_out[lane * 3 + 2] = 0.0f;
    }
}

extern "C" void kernel_launch(void* const* d_in, const int* in_sizes, int n_in,
                              void* d_out, int out_size, void* d_ws, size_t ws_size,
                              hipStream_t stream) {
    const float* pc1 = (const float*)d_in[0];   // (1, 8192, 3)  queries
    const float* pc2 = (const float*)d_in[1];   // (1, 32768, 3) points
    float* out = (float*)d_out;

    dim3 grid(N1 / 4);    // 4 waves per 256-thread block, one wave per query
    dim3 block(256);
    ball_query_kernel<<<grid, block, 0, stream>>>(pc1, pc2, out);
}